// Round 5
// baseline (193.581 us; speedup 1.0000x reference)
//
#include <hip/hip_runtime.h>
#include <stdint.h>

#define DI __device__ __forceinline__

typedef __attribute__((ext_vector_type(8))) __bf16 bf16x8;
typedef __attribute__((ext_vector_type(8))) unsigned short u16x8;
typedef __attribute__((ext_vector_type(4))) float f32x4;
typedef __attribute__((ext_vector_type(4))) uint32_t u32x4;
typedef unsigned short u16;

constexpr int Bb = 4, Cc = 256, Ss = 4096, HD = 64;
constexpr int ELEMS = Bb * Cc * Ss;  // 4194304

DI float bf2f(u16 h) { union { unsigned u; float f; } x; x.u = ((unsigned)h) << 16; return x.f; }
DI u16 f2bf(float f) {
  union { float f; unsigned u; } x; x.f = f;
  return (u16)((x.u + 0x7FFFu + ((x.u >> 16) & 1u)) >> 16);
}
DI uint32_t pack2bf_trunc(float a, float b) {  // low16=bf(a), high16=bf(b), truncating
  union { float f; uint32_t u; } xa, xb;
  xa.f = a; xb.f = b;
  return __builtin_amdgcn_perm(xb.u, xa.u, 0x07060302u);
}
DI float truncbf(float f) {  // value of the truncated-bf16 representation
  union { float f; unsigned u; } x; x.f = f; x.u &= 0xFFFF0000u; return x.f;
}
DI bf16x8 ldfrag(const u16* p) { return __builtin_bit_cast(bf16x8, *(const u16x8*)p); }

// async global->LDS DMA, 16B per lane. LDS dest = wave-uniform base + lane*16 (linear);
// source address is per-lane (carries the swizzle).
DI void g2l16(const u16* g, u16* l) {
  __builtin_amdgcn_global_load_lds((const __attribute__((address_space(1))) uint32_t*)(const void*)g,
                                   (__attribute__((address_space(3))) uint32_t*)(void*)l, 16, 0, 0);
}

// ---------------- kernel 0: x (B,C,S) fp32 -> xt (B,S,C) bf16; + weight conversion fused ----------------
__global__ __launch_bounds__(256) void k_transpose(const float* __restrict__ x, u16* __restrict__ xt,
                                                   const float* __restrict__ wq, const float* __restrict__ wo,
                                                   u16* __restrict__ wqb, u16* __restrict__ wob) {
  __shared__ u16 T[64][72];
  const int st = blockIdx.x, ct = blockIdx.y, b = blockIdx.z;
  const int tid = threadIdx.x;
  // fused weight conversion: 1024 blocks x 256 threads == 262144 == 196608 + 65536
  {
    int flat = blockIdx.x + 64 * blockIdx.y + 256 * blockIdx.z;
    int widx = flat * 256 + tid;
    if (widx < 196608) wqb[widx] = f2bf(wq[widx]);
    else wob[widx - 196608] = f2bf(wo[widx - 196608]);
  }
#pragma unroll
  for (int e = 0; e < 2; e++) {
    int ss = tid + e * 256;
    int r = ss >> 3, seg = ss & 7;
    size_t base = ((size_t)(b * Cc + ct * 64 + r) << 12) + st * 64 + seg * 8;
    u16x8 t;
#pragma unroll
    for (int j = 0; j < 8; j++) t[j] = f2bf(x[base + j]);
    *(u16x8*)&T[r][(seg ^ ((r >> 3) & 7)) * 8] = t;
  }
  __syncthreads();
#pragma unroll
  for (int e = 0; e < 2; e++) {
    int ss = tid + e * 256;
    int sr = ss >> 3, cseg = ss & 7;
    u16x8 o;
#pragma unroll
    for (int j = 0; j < 8; j++) {
      int row = cseg * 8 + j;
      o[j] = T[row][(((sr >> 3) ^ cseg) * 8) + (sr & 7)];
    }
    *(u16x8*)(xt + ((size_t)(b * Ss + st * 64 + sr) << 8) + ct * 64 + cseg * 8) = o;
  }
}

// ---- shared GEMM staging: rows [r0,r0+128) x cols [k0,k0+32), pitch-40 LDS ----
DI void stage_tile(const u16* __restrict__ src, int pitch, int r0, int k0, u16 (*dst)[40], int tid) {
#pragma unroll
  for (int e = 0; e < 2; e++) {
    int c = tid + e * 256;
    int row = c >> 2, seg = c & 3;
    u16x8 t = *(const u16x8*)(src + (size_t)(r0 + row) * pitch + k0 + seg * 8);
    *(u16x8*)&dst[row][seg * 8] = t;
  }
}

// ---------------- kernel 1: qkv GEMM.  q:[bh][s][64]*(0.125*log2e)  k,v:[bh][s][64] ----------------
__global__ __launch_bounds__(256) void k_qkv(const u16* __restrict__ xt, const u16* __restrict__ w,
                                             const float* __restrict__ bias,
                                             u16* __restrict__ q, u16* __restrict__ kk_, u16* __restrict__ vv_) {
  __shared__ u16 As[128][40], Bs[128][40];
  const int tid = threadIdx.x;
  const int wv = tid >> 6, lane = tid & 63;
  const int wm = wv >> 1, wn = wv & 1;
  const int lr = lane & 15, quad = lane >> 4;
  const int r0 = blockIdx.x * 128;
  const int j0 = blockIdx.y * 128;
  f32x4 acc[4][4] = {};
  for (int k0 = 0; k0 < 256; k0 += 32) {
    __syncthreads();
    stage_tile(xt, 256, r0, k0, As, tid);
    stage_tile(w, 256, j0, k0, Bs, tid);
    __syncthreads();
    bf16x8 a[4], b[4];
#pragma unroll
    for (int mt = 0; mt < 4; mt++) a[mt] = ldfrag(&As[wm * 64 + mt * 16 + lr][quad * 8]);
#pragma unroll
    for (int nt = 0; nt < 4; nt++) b[nt] = ldfrag(&Bs[wn * 64 + nt * 16 + lr][quad * 8]);
#pragma unroll
    for (int mt = 0; mt < 4; mt++)
#pragma unroll
      for (int nt = 0; nt < 4; nt++)
        acc[mt][nt] = __builtin_amdgcn_mfma_f32_16x16x32_bf16(a[mt], b[nt], acc[mt][nt], 0, 0, 0);
  }
#pragma unroll
  for (int nt = 0; nt < 4; nt++) {
    int j = j0 + wn * 64 + nt * 16 + lr;
    float bj = bias[j];
    int part = j >> 8, cc = j & 255, head = cc >> 6, d = cc & 63;
    u16* outp = (part == 0) ? q : (part == 1) ? kk_ : vv_;
    float sc = (part == 0) ? 0.18033688f : 1.0f;  // 0.125*log2(e), exp2-domain scores
#pragma unroll
    for (int mt = 0; mt < 4; mt++)
#pragma unroll
      for (int rg = 0; rg < 4; rg++) {
        int row = r0 + wm * 64 + mt * 16 + quad * 4 + rg;
        int b_ = row >> 12, s = row & 4095;
        outp[((size_t)((b_ * 4 + head) * Ss + s) << 6) + d] = f2bf((acc[mt][nt][rg] + bj) * sc);
      }
  }
}

// ---------------- v [bh][s][64] -> vt [bh][d][chunk*64 + slot] (key-permuted transpose) ----------------
__global__ __launch_bounds__(256) void k_vt(const u16* __restrict__ v, u16* __restrict__ vt) {
  __shared__ u16 T[64][72];
  const int chunk = blockIdx.x, bh = blockIdx.y;
  const int tid = threadIdx.x;
#pragma unroll
  for (int e = 0; e < 2; e++) {
    int row = (tid >> 3) + e * 32, seg = tid & 7;
    *(u16x8*)&T[row][(seg ^ ((row >> 3) & 7)) * 8] =
        *(const u16x8*)(v + ((size_t)(bh * Ss + chunk * 64 + row) << 6) + seg * 8);
  }
  __syncthreads();
#pragma unroll
  for (int e = 0; e < 2; e++) {
    int d = (tid >> 3) + e * 32, seg = tid & 7;
    u16x8 o;
#pragma unroll
    for (int j = 0; j < 8; j++) {
      int slot = seg * 8 + j;
      int t = (((slot >> 5) & 1) << 1) | ((slot >> 2) & 1);
      int w6 = t * 16 + (((slot >> 3) & 3) << 2) + (slot & 3);
      o[j] = T[w6][(((d >> 3) ^ ((w6 >> 3) & 7)) * 8) + (d & 7)];
    }
    *(u16x8*)(vt + ((size_t)(bh * 64 + d) << 12) + chunk * 64 + seg * 8) = o;
  }
}

// ---------------- kernel 2: flash attention, S^T form, exp2 no-max softmax ----------------
// 32 q-rows per wave (128/block): halves per-wave register state (O[2][4]=32 acc, ~110-125
// unified total) -> 4 waves/SIMD resident, 4 blocks/CU (grid 1024 at nsplit=2). At 2 waves/SIMD
// the pipes ran fully serialized (MfmaUtil 42 + VALUBusy 39 ~= serial sum); more waves is the
// only overlap mechanism left. l is accumulated on the VALU from St (sum of truncated-bf16 P,
// bit-consistent with the old ones-MFMA) -- removes 11% of matrix-pipe work + 20 regs.
// K/V staged via global_load_lds DMA with pre-swizzled per-lane source (linear LDS dest),
// double-buffered; barrier at chunk end drains the DMA.
__global__ __launch_bounds__(256, 3) void k_attn(const u16* __restrict__ Q, const u16* __restrict__ K,
                                                 const u16* __restrict__ VT, u16* __restrict__ AO,
                                                 u16* __restrict__ AOP, float* __restrict__ lpart,
                                                 int nsplit) {
  __shared__ u16 Kl[2][64][64];
  __shared__ u16 Vl[2][64][64];
  const int tid = threadIdx.x;
  const int wv = tid >> 6, lane = tid & 63;
  const int lr = lane & 15, quad = lane >> 4;
  const int bh = blockIdx.y;
  const int b_ = bh >> 2, head = bh & 3;
  const int qbase = blockIdx.x * 128 + wv * 32;
  const int sp = blockIdx.z;
  const int nchunk = 64 / nsplit, kcg0 = sp * nchunk;
  const u16* Qh = Q + (size_t)bh * Ss * HD;
  const u16* Kh = K + (size_t)bh * Ss * HD;
  const u16* Vh = VT + (size_t)bh * HD * Ss;  // [d][perm(s)]

  bf16x8 qb[2][2];
#pragma unroll
  for (int nt = 0; nt < 2; nt++)
#pragma unroll
    for (int ks = 0; ks < 2; ks++)
      qb[nt][ks] = ldfrag(Qh + (size_t)(qbase + nt * 16 + lr) * HD + ks * 32 + quad * 8);

  f32x4 O[2][4] = {};
  float lsum[2] = {0.f, 0.f};

  // DMA staging: wave wv covers rows wv*16..wv*16+15 of both 64x64 tiles.
  // per-lane source granule = (l&7) ^ (l>>3) implements the XOR swizzle at the source.
  const int lrow = lane >> 3;
  const int lseg = ((lane & 7) ^ lrow) * 8;
  const int kd0 = wv * 16 + lrow;
  const u16* pK0 = Kh + ((size_t)(kcg0 * 64 + kd0) << 6) + lseg;
  const u16* pK1 = pK0 + (8 << 6);
  const u16* pV0 = Vh + ((size_t)kd0 << 12) + kcg0 * 64 + lseg;
  const u16* pV1 = pV0 + ((size_t)8 << 12);
  auto stage = [&](int buf) {
    g2l16(pK0, &Kl[buf][wv * 16][0]);
    g2l16(pK1, &Kl[buf][wv * 16 + 8][0]);
    g2l16(pV0, &Vl[buf][wv * 16][0]);
    g2l16(pV1, &Vl[buf][wv * 16 + 8][0]);
    pK0 += 4096; pK1 += 4096; pV0 += 64; pV1 += 64;  // next chunk
  };

  stage(0);
  __syncthreads();

  for (int kc = 0; kc < nchunk; kc++) {
    const int cur = kc & 1;
    if (kc + 1 < nchunk) stage(cur ^ 1);  // async into other buffer; drains at loop-end barrier

    u32x4 pa[2][2];  // [kv-half][q-group]: packed bf16 P fragments (PV A-operands)
#pragma unroll
    for (int t = 0; t < 4; t++) {  // 16-row kv tiles
      const int krow = t * 16 + lr;
      bf16x8 ka0 = ldfrag(&Kl[cur][krow][(quad ^ (lr & 7)) * 8]);
      bf16x8 ka1 = ldfrag(&Kl[cur][krow][((4 + quad) ^ (lr & 7)) * 8]);
      f32x4 St[2] = {};
      __builtin_amdgcn_s_setprio(1);
#pragma unroll
      for (int nt = 0; nt < 2; nt++)
        St[nt] = __builtin_amdgcn_mfma_f32_16x16x32_bf16(ka0, qb[nt][0], St[nt], 0, 0, 0);
#pragma unroll
      for (int nt = 0; nt < 2; nt++)
        St[nt] = __builtin_amdgcn_mfma_f32_16x16x32_bf16(ka1, qb[nt][1], St[nt], 0, 0, 0);
      __builtin_amdgcn_s_setprio(0);
      const int h = t >> 1, k2 = (t & 1) * 2;
#pragma unroll
      for (int nt = 0; nt < 2; nt++) {
        float p0 = __builtin_amdgcn_exp2f(St[nt][0]);
        float p1 = __builtin_amdgcn_exp2f(St[nt][1]);
        float p2 = __builtin_amdgcn_exp2f(St[nt][2]);
        float p3 = __builtin_amdgcn_exp2f(St[nt][3]);
        pa[h][nt][k2] = pack2bf_trunc(p0, p1);
        pa[h][nt][k2 + 1] = pack2bf_trunc(p2, p3);
        // l accumulation on VALU: sum the truncated-bf16 values (== what ones-MFMA summed)
        lsum[nt] += (truncbf(p0) + truncbf(p1)) + (truncbf(p2) + truncbf(p3));
      }
    }
#pragma unroll
    for (int h = 0; h < 2; h++)
#pragma unroll
      for (int dt = 0; dt < 4; dt++) {
        bf16x8 vb = ldfrag(&Vl[cur][dt * 16 + lr][((h * 4 + quad) ^ (lr & 7)) * 8]);
        __builtin_amdgcn_s_setprio(1);
#pragma unroll
        for (int mt = 0; mt < 2; mt++)
          O[mt][dt] = __builtin_amdgcn_mfma_f32_16x16x32_bf16(
              __builtin_bit_cast(bf16x8, pa[h][mt]), vb, O[mt][dt], 0, 0, 0);
        __builtin_amdgcn_s_setprio(0);
      }
    __syncthreads();
  }

  // l finalize: lsum[nt] holds partial sums (this lane's quad rows) for q = nt*16 + (lane&15).
  // butterfly over quad groups (xor 16/32 keeps lane&15), then redistribute to O's row layout
  // (q-row = quad*4+rg) via bpermute.
  float lfull[2];
#pragma unroll
  for (int nt = 0; nt < 2; nt++) {
    float r = lsum[nt] + __shfl_xor(lsum[nt], 16, 64);
    r += __shfl_xor(r, 32, 64);
    lfull[nt] = r;
  }
  float lval[2][4];
#pragma unroll
  for (int mt = 0; mt < 2; mt++)
#pragma unroll
    for (int rg = 0; rg < 4; rg++)
      lval[mt][rg] = __shfl(lfull[mt], quad * 4 + rg, 64);

  // epilogue: normalize by this split's l, write bf16 (AO if nsplit==1, else partial slot sp)
  u16* dst = (nsplit == 1) ? AO : (AOP + (size_t)sp * ELEMS);
  if (nsplit > 1 && lr == 0) {
    float* lp = lpart + (size_t)sp * (16 * Ss) + bh * Ss;
#pragma unroll
    for (int mt = 0; mt < 2; mt++)
#pragma unroll
      for (int rg = 0; rg < 4; rg++) lp[qbase + mt * 16 + quad * 4 + rg] = lval[mt][rg];
  }
#pragma unroll
  for (int mt = 0; mt < 2; mt++)
#pragma unroll
    for (int rg = 0; rg < 4; rg++) {
      float inv = 1.0f / lval[mt][rg];
      int s = qbase + mt * 16 + quad * 4 + rg;
#pragma unroll
      for (int dt = 0; dt < 4; dt++)
        dst[((size_t)(b_ * Ss + s) << 8) + head * 64 + dt * 16 + lr] = f2bf(O[mt][dt][rg] * inv);
    }
}

// ---------------- kernel 3 (fused combine + oproj): y^T = w_o * combine(aop)^T + b_o ----------------
__global__ __launch_bounds__(256) void k_oproj(const u16* __restrict__ wo, const u16* __restrict__ ao,
                                               const u16* __restrict__ AOP, const float* __restrict__ lpart,
                                               const float* __restrict__ bo, float* __restrict__ y, int nsplit) {
  __shared__ u16 As[128][40], Bs[128][40];
  const int tid = threadIdx.x;
  const int wv = tid >> 6, lane = tid & 63;
  const int wm = wv >> 1, wn = wv & 1;
  const int lr = lane & 15, quad = lane >> 4;
  const int n0 = blockIdx.x * 128;
  const int m0 = blockIdx.y * 128;
  f32x4 acc[4][4] = {};
  for (int k0 = 0; k0 < 256; k0 += 32) {
    __syncthreads();
    stage_tile(wo, 256, m0, k0, As, tid);
#pragma unroll
    for (int e = 0; e < 2; e++) {  // B: 128 n-rows x 32 c-cols, l-weighted combine
      int c = tid + e * 256;
      int row = c >> 2, seg = c & 3;
      int bs = n0 + row, cc = k0 + seg * 8;
      u16x8 t;
      if (nsplit == 1) {
        t = *(const u16x8*)(ao + ((size_t)bs << 8) + cc);
      } else {
        int b = bs >> 12, s = bs & 4095, head = cc >> 6;
        int li = (b * 4 + head) * Ss + s;
        float accv[8] = {0.f, 0.f, 0.f, 0.f, 0.f, 0.f, 0.f, 0.f};
        float lsum = 0.f;
        for (int spl = 0; spl < nsplit; spl++) {
          float l = lpart[(size_t)spl * (16 * Ss) + li];
          u16x8 a = *(const u16x8*)(AOP + (size_t)spl * ELEMS + ((size_t)bs << 8) + cc);
          lsum += l;
#pragma unroll
          for (int i = 0; i < 8; i++) accv[i] += l * bf2f(a[i]);
        }
        float inv = 1.0f / lsum;
#pragma unroll
        for (int i = 0; i < 8; i++) t[i] = f2bf(accv[i] * inv);
      }
      *(u16x8*)&Bs[row][seg * 8] = t;
    }
    __syncthreads();
    bf16x8 a[4], b[4];
#pragma unroll
    for (int mt = 0; mt < 4; mt++) a[mt] = ldfrag(&As[wm * 64 + mt * 16 + lr][quad * 8]);
#pragma unroll
    for (int nt = 0; nt < 4; nt++) b[nt] = ldfrag(&Bs[wn * 64 + nt * 16 + lr][quad * 8]);
#pragma unroll
    for (int mt = 0; mt < 4; mt++)
#pragma unroll
      for (int nt = 0; nt < 4; nt++)
        acc[mt][nt] = __builtin_amdgcn_mfma_f32_16x16x32_bf16(a[mt], b[nt], acc[mt][nt], 0, 0, 0);
  }
#pragma unroll
  for (int mt = 0; mt < 4; mt++)
#pragma unroll
    for (int rg = 0; rg < 4; rg++) {
      int c = m0 + wm * 64 + mt * 16 + quad * 4 + rg;
      float bc = bo[c];
#pragma unroll
      for (int nt = 0; nt < 4; nt++) {
        int col = n0 + wn * 64 + nt * 16 + lr;
        int b_ = col >> 12, s = col & 4095;
        y[((size_t)(b_ * Cc + c) << 12) + s] = acc[mt][nt][rg] + bc;
      }
    }
}

extern "C" void kernel_launch(void* const* d_in, const int* in_sizes, int n_in,
                              void* d_out, int out_size, void* d_ws, size_t ws_size,
                              hipStream_t stream) {
  const float* x = (const float*)d_in[0];
  const float* w_qkv = (const float*)d_in[1];
  const float* b_qkv = (const float*)d_in[2];
  const float* w_o = (const float*)d_in[3];
  const float* b_o = (const float*)d_in[4];
  float* y = (float*)d_out;
  u16* ws = (u16*)d_ws;
  u16* xt = ws;                        // [0, E) — reused as ao (nsplit==1 fallback)
  u16* q = ws + (size_t)ELEMS;
  u16* k = ws + (size_t)2 * ELEMS;
  u16* vt = ws + (size_t)3 * ELEMS;
  u16* ao = xt;
  u16* wqb = ws + (size_t)4 * ELEMS;   // 196608
  u16* wob = wqb + 196608;             // 65536
  const size_t Wu16 = (size_t)4 * ELEMS + 262144;
  // need(n) bytes = bf16 ws incl. n partial slabs, + n*16*Ss f32 for lpart
  auto need = [&](int n) { return (Wu16 + (size_t)n * ELEMS) * 2 + (size_t)n * 16 * Ss * 4; };
  const int nsplit = (ws_size >= need(2)) ? 2 : 1;
  u16* aop = ws + Wu16;                // nsplit*ELEMS u16 normalized partials
  u16* v = aop;                        // plain V aliases aop (dead before k_attn writes)
  float* lpart = (float*)(aop + (size_t)nsplit * ELEMS);

  k_transpose<<<dim3(64, 4, 4), 256, 0, stream>>>(x, xt, w_qkv, w_o, wqb, wob);
  k_qkv<<<dim3(128, 6), 256, 0, stream>>>(xt, wqb, b_qkv, q, k, v);
  k_vt<<<dim3(64, 16), 256, 0, stream>>>(v, vt);
  k_attn<<<dim3(32, 16, nsplit), 256, 0, stream>>>(q, k, vt, ao, aop, lpart, nsplit);
  k_oproj<<<dim3(128, 2), 256, 0, stream>>>(wob, ao, aop, lpart, b_o, y, nsplit);
}

// Round 6
// 179.004 us; speedup vs baseline: 1.0814x; 1.0814x over previous
//
#include <hip/hip_runtime.h>
#include <stdint.h>

#define DI __device__ __forceinline__

typedef __attribute__((ext_vector_type(8))) __bf16 bf16x8;
typedef __attribute__((ext_vector_type(8))) unsigned short u16x8;
typedef __attribute__((ext_vector_type(4))) float f32x4;
typedef __attribute__((ext_vector_type(4))) uint32_t u32x4;
typedef unsigned short u16;

constexpr int Bb = 4, Cc = 256, Ss = 4096, HD = 64;
constexpr int ELEMS = Bb * Cc * Ss;  // 4194304

DI float bf2f(u16 h) { union { unsigned u; float f; } x; x.u = ((unsigned)h) << 16; return x.f; }
DI u16 f2bf(float f) {
  union { float f; unsigned u; } x; x.f = f;
  return (u16)((x.u + 0x7FFFu + ((x.u >> 16) & 1u)) >> 16);
}
DI uint32_t pack2bf_trunc(float a, float b) {  // low16=bf(a), high16=bf(b), truncating
  union { float f; uint32_t u; } xa, xb;
  xa.f = a; xb.f = b;
  return __builtin_amdgcn_perm(xb.u, xa.u, 0x07060302u);
}
DI bf16x8 ldfrag(const u16* p) { return __builtin_bit_cast(bf16x8, *(const u16x8*)p); }

// async global->LDS DMA, 16B per lane. LDS dest = wave-uniform base + lane*16 (linear);
// source address is per-lane (carries the swizzle).
DI void g2l16(const u16* g, u16* l) {
  __builtin_amdgcn_global_load_lds((const __attribute__((address_space(1))) uint32_t*)(const void*)g,
                                   (__attribute__((address_space(3))) uint32_t*)(void*)l, 16, 0, 0);
}

// ---------------- kernel 0: x (B,C,S) fp32 -> xt (B,S,C) bf16; + weight conversion fused ----------------
__global__ __launch_bounds__(256) void k_transpose(const float* __restrict__ x, u16* __restrict__ xt,
                                                   const float* __restrict__ wq, const float* __restrict__ wo,
                                                   u16* __restrict__ wqb, u16* __restrict__ wob) {
  __shared__ u16 T[64][72];
  const int st = blockIdx.x, ct = blockIdx.y, b = blockIdx.z;
  const int tid = threadIdx.x;
  // fused weight conversion: 1024 blocks x 256 threads == 262144 == 196608 + 65536
  {
    int flat = blockIdx.x + 64 * blockIdx.y + 256 * blockIdx.z;
    int widx = flat * 256 + tid;
    if (widx < 196608) wqb[widx] = f2bf(wq[widx]);
    else wob[widx - 196608] = f2bf(wo[widx - 196608]);
  }
#pragma unroll
  for (int e = 0; e < 2; e++) {
    int ss = tid + e * 256;
    int r = ss >> 3, seg = ss & 7;
    size_t base = ((size_t)(b * Cc + ct * 64 + r) << 12) + st * 64 + seg * 8;
    u16x8 t;
#pragma unroll
    for (int j = 0; j < 8; j++) t[j] = f2bf(x[base + j]);
    *(u16x8*)&T[r][(seg ^ ((r >> 3) & 7)) * 8] = t;
  }
  __syncthreads();
#pragma unroll
  for (int e = 0; e < 2; e++) {
    int ss = tid + e * 256;
    int sr = ss >> 3, cseg = ss & 7;
    u16x8 o;
#pragma unroll
    for (int j = 0; j < 8; j++) {
      int row = cseg * 8 + j;
      o[j] = T[row][(((sr >> 3) ^ cseg) * 8) + (sr & 7)];
    }
    *(u16x8*)(xt + ((size_t)(b * Ss + st * 64 + sr) << 8) + ct * 64 + cseg * 8) = o;
  }
}

// ---- shared GEMM staging: rows [r0,r0+128) x cols [k0,k0+32), pitch-40 LDS ----
DI void stage_tile(const u16* __restrict__ src, int pitch, int r0, int k0, u16 (*dst)[40], int tid) {
#pragma unroll
  for (int e = 0; e < 2; e++) {
    int c = tid + e * 256;
    int row = c >> 2, seg = c & 3;
    u16x8 t = *(const u16x8*)(src + (size_t)(r0 + row) * pitch + k0 + seg * 8);
    *(u16x8*)&dst[row][seg * 8] = t;
  }
}

// ---------------- kernel 1: qkv GEMM.  q:[bh][s][64]*(0.125*log2e)  k,v:[bh][s][64] ----------------
__global__ __launch_bounds__(256) void k_qkv(const u16* __restrict__ xt, const u16* __restrict__ w,
                                             const float* __restrict__ bias,
                                             u16* __restrict__ q, u16* __restrict__ kk_, u16* __restrict__ vv_) {
  __shared__ u16 As[128][40], Bs[128][40];
  const int tid = threadIdx.x;
  const int wv = tid >> 6, lane = tid & 63;
  const int wm = wv >> 1, wn = wv & 1;
  const int lr = lane & 15, quad = lane >> 4;
  const int r0 = blockIdx.x * 128;
  const int j0 = blockIdx.y * 128;
  f32x4 acc[4][4] = {};
  for (int k0 = 0; k0 < 256; k0 += 32) {
    __syncthreads();
    stage_tile(xt, 256, r0, k0, As, tid);
    stage_tile(w, 256, j0, k0, Bs, tid);
    __syncthreads();
    bf16x8 a[4], b[4];
#pragma unroll
    for (int mt = 0; mt < 4; mt++) a[mt] = ldfrag(&As[wm * 64 + mt * 16 + lr][quad * 8]);
#pragma unroll
    for (int nt = 0; nt < 4; nt++) b[nt] = ldfrag(&Bs[wn * 64 + nt * 16 + lr][quad * 8]);
#pragma unroll
    for (int mt = 0; mt < 4; mt++)
#pragma unroll
      for (int nt = 0; nt < 4; nt++)
        acc[mt][nt] = __builtin_amdgcn_mfma_f32_16x16x32_bf16(a[mt], b[nt], acc[mt][nt], 0, 0, 0);
  }
#pragma unroll
  for (int nt = 0; nt < 4; nt++) {
    int j = j0 + wn * 64 + nt * 16 + lr;
    float bj = bias[j];
    int part = j >> 8, cc = j & 255, head = cc >> 6, d = cc & 63;
    u16* outp = (part == 0) ? q : (part == 1) ? kk_ : vv_;
    float sc = (part == 0) ? 0.18033688f : 1.0f;  // 0.125*log2(e), exp2-domain scores
#pragma unroll
    for (int mt = 0; mt < 4; mt++)
#pragma unroll
      for (int rg = 0; rg < 4; rg++) {
        int row = r0 + wm * 64 + mt * 16 + quad * 4 + rg;
        int b_ = row >> 12, s = row & 4095;
        outp[((size_t)((b_ * 4 + head) * Ss + s) << 6) + d] = f2bf((acc[mt][nt][rg] + bj) * sc);
      }
  }
}

// ---------------- v [bh][s][64] -> vt [bh][d][chunk*64 + slot] (key-permuted transpose) ----------------
__global__ __launch_bounds__(256) void k_vt(const u16* __restrict__ v, u16* __restrict__ vt) {
  __shared__ u16 T[64][72];
  const int chunk = blockIdx.x, bh = blockIdx.y;
  const int tid = threadIdx.x;
#pragma unroll
  for (int e = 0; e < 2; e++) {
    int row = (tid >> 3) + e * 32, seg = tid & 7;
    *(u16x8*)&T[row][(seg ^ ((row >> 3) & 7)) * 8] =
        *(const u16x8*)(v + ((size_t)(bh * Ss + chunk * 64 + row) << 6) + seg * 8);
  }
  __syncthreads();
#pragma unroll
  for (int e = 0; e < 2; e++) {
    int d = (tid >> 3) + e * 32, seg = tid & 7;
    u16x8 o;
#pragma unroll
    for (int j = 0; j < 8; j++) {
      int slot = seg * 8 + j;
      int t = (((slot >> 5) & 1) << 1) | ((slot >> 2) & 1);
      int w6 = t * 16 + (((slot >> 3) & 3) << 2) + (slot & 3);
      o[j] = T[w6][(((d >> 3) ^ ((w6 >> 3) & 7)) * 8) + (d & 7)];
    }
    *(u16x8*)(vt + ((size_t)(bh * 64 + d) << 12) + chunk * 64 + seg * 8) = o;
  }
}

// ---------------- kernel 2: flash attention, S^T form, exp2 no-max softmax ----------------
// 8-wave (512-thread) blocks of 32-q waves, 256 q-rows/block: r4's work distribution
// (same per-CU staging amortization, same MFMA work) but 4 waves/SIMD of half-state waves —
// the independent instruction streams the 2-wave/SIMD variants lacked. l stays on the
// ones-MFMA (r5 showed moving it to VALU hurts: VALU is the contended pipe).
// Staging: one g2l16 per thread per tile (512 lanes x 16B = 8KB tile), pre-swizzled source.
// grid (16,16,2) = 512 blocks = 2 blocks/CU; LDS 32KB; target unified regs ~110 < 128 cap.
__global__ __launch_bounds__(512, 4) void k_attn(const u16* __restrict__ Q, const u16* __restrict__ K,
                                                 const u16* __restrict__ VT, u16* __restrict__ AO,
                                                 u16* __restrict__ AOP, float* __restrict__ lpart,
                                                 int nsplit) {
  __shared__ u16 Kl[2][64][64];
  __shared__ u16 Vl[2][64][64];
  const int tid = threadIdx.x;
  const int wv = tid >> 6, lane = tid & 63;
  const int lr = lane & 15, quad = lane >> 4;
  const int bh = blockIdx.y;
  const int b_ = bh >> 2, head = bh & 3;
  const int qbase = blockIdx.x * 256 + wv * 32;
  const int sp = blockIdx.z;
  const int nchunk = 64 / nsplit, kcg0 = sp * nchunk;
  const u16* Qh = Q + (size_t)bh * Ss * HD;
  const u16* Kh = K + (size_t)bh * Ss * HD;
  const u16* Vh = VT + (size_t)bh * HD * Ss;  // [d][perm(s)]

  bf16x8 qb[2][2];
#pragma unroll
  for (int nt = 0; nt < 2; nt++)
#pragma unroll
    for (int ks = 0; ks < 2; ks++)
      qb[nt][ks] = ldfrag(Qh + (size_t)(qbase + nt * 16 + lr) * HD + ks * 32 + quad * 8);

  u16x8 ov;
#pragma unroll
  for (int j = 0; j < 8; j++) ov[j] = 0x3F80;
  const bf16x8 ones = __builtin_bit_cast(bf16x8, ov);

  f32x4 O[2][4] = {};
  f32x4 lacc[2] = {};

  // DMA staging: 8 waves cover 64 rows (wave wv: rows wv*8..wv*8+7). Lane l writes LDS
  // granule (row = wv*8 + l>>3, slot = l&7); source granule = (l&7) ^ (row&7) = (l&7)^(l>>3).
  const int srow = wv * 8 + (lane >> 3);
  const int sseg = ((lane & 7) ^ (lane >> 3)) * 8;
  const u16* pK = Kh + ((size_t)(kcg0 * 64 + srow) << 6) + sseg;
  const u16* pV = Vh + ((size_t)srow << 12) + kcg0 * 64 + sseg;
  auto stage = [&](int buf) {
    g2l16(pK, &Kl[buf][wv * 8][0]);
    g2l16(pV, &Vl[buf][wv * 8][0]);
    pK += 4096; pV += 64;  // next chunk
  };

  stage(0);
  __syncthreads();

  for (int kc = 0; kc < nchunk; kc++) {
    const int cur = kc & 1;
    if (kc + 1 < nchunk) stage(cur ^ 1);  // async into other buffer; drains at loop-end barrier

    u32x4 pa[2][2];  // [kv-half][q-group]: packed bf16 P fragments (PV A-operands)
#pragma unroll
    for (int t = 0; t < 4; t++) {  // 16-row kv tiles
      const int krow = t * 16 + lr;
      bf16x8 ka0 = ldfrag(&Kl[cur][krow][(quad ^ (lr & 7)) * 8]);
      bf16x8 ka1 = ldfrag(&Kl[cur][krow][((4 + quad) ^ (lr & 7)) * 8]);
      f32x4 St[2] = {};
      __builtin_amdgcn_s_setprio(1);
#pragma unroll
      for (int nt = 0; nt < 2; nt++)
        St[nt] = __builtin_amdgcn_mfma_f32_16x16x32_bf16(ka0, qb[nt][0], St[nt], 0, 0, 0);
#pragma unroll
      for (int nt = 0; nt < 2; nt++)
        St[nt] = __builtin_amdgcn_mfma_f32_16x16x32_bf16(ka1, qb[nt][1], St[nt], 0, 0, 0);
      __builtin_amdgcn_s_setprio(0);
      const int h = t >> 1, k2 = (t & 1) * 2;
#pragma unroll
      for (int nt = 0; nt < 2; nt++) {
        float p0 = __builtin_amdgcn_exp2f(St[nt][0]);
        float p1 = __builtin_amdgcn_exp2f(St[nt][1]);
        float p2 = __builtin_amdgcn_exp2f(St[nt][2]);
        float p3 = __builtin_amdgcn_exp2f(St[nt][3]);
        pa[h][nt][k2] = pack2bf_trunc(p0, p1);
        pa[h][nt][k2 + 1] = pack2bf_trunc(p2, p3);
      }
    }
#pragma unroll
    for (int h = 0; h < 2; h++) {
#pragma unroll
      for (int dt = 0; dt < 4; dt++) {
        bf16x8 vb = ldfrag(&Vl[cur][dt * 16 + lr][((h * 4 + quad) ^ (lr & 7)) * 8]);
        __builtin_amdgcn_s_setprio(1);
#pragma unroll
        for (int mt = 0; mt < 2; mt++)
          O[mt][dt] = __builtin_amdgcn_mfma_f32_16x16x32_bf16(
              __builtin_bit_cast(bf16x8, pa[h][mt]), vb, O[mt][dt], 0, 0, 0);
        __builtin_amdgcn_s_setprio(0);
      }
#pragma unroll
      for (int mt = 0; mt < 2; mt++)
        lacc[mt] = __builtin_amdgcn_mfma_f32_16x16x32_bf16(
            __builtin_bit_cast(bf16x8, pa[h][mt]), ones, lacc[mt], 0, 0, 0);
    }
    __syncthreads();
  }

  // epilogue: normalize by this split's l, write bf16 (AO if nsplit==1, else partial slot sp)
  u16* dst = (nsplit == 1) ? AO : (AOP + (size_t)sp * ELEMS);
  if (nsplit > 1 && lr == 0) {
    float* lp = lpart + (size_t)sp * (16 * Ss) + bh * Ss;
#pragma unroll
    for (int mt = 0; mt < 2; mt++)
#pragma unroll
      for (int rg = 0; rg < 4; rg++) lp[qbase + mt * 16 + quad * 4 + rg] = lacc[mt][rg];
  }
#pragma unroll
  for (int mt = 0; mt < 2; mt++)
#pragma unroll
    for (int rg = 0; rg < 4; rg++) {
      float inv = 1.0f / lacc[mt][rg];
      int s = qbase + mt * 16 + quad * 4 + rg;
#pragma unroll
      for (int dt = 0; dt < 4; dt++)
        dst[((size_t)(b_ * Ss + s) << 8) + head * 64 + dt * 16 + lr] = f2bf(O[mt][dt][rg] * inv);
    }
}

// ---------------- kernel 3 (fused combine + oproj): y^T = w_o * combine(aop)^T + b_o ----------------
__global__ __launch_bounds__(256) void k_oproj(const u16* __restrict__ wo, const u16* __restrict__ ao,
                                               const u16* __restrict__ AOP, const float* __restrict__ lpart,
                                               const float* __restrict__ bo, float* __restrict__ y, int nsplit) {
  __shared__ u16 As[128][40], Bs[128][40];
  const int tid = threadIdx.x;
  const int wv = tid >> 6, lane = tid & 63;
  const int wm = wv >> 1, wn = wv & 1;
  const int lr = lane & 15, quad = lane >> 4;
  const int n0 = blockIdx.x * 128;
  const int m0 = blockIdx.y * 128;
  f32x4 acc[4][4] = {};
  for (int k0 = 0; k0 < 256; k0 += 32) {
    __syncthreads();
    stage_tile(wo, 256, m0, k0, As, tid);
#pragma unroll
    for (int e = 0; e < 2; e++) {  // B: 128 n-rows x 32 c-cols, l-weighted combine
      int c = tid + e * 256;
      int row = c >> 2, seg = c & 3;
      int bs = n0 + row, cc = k0 + seg * 8;
      u16x8 t;
      if (nsplit == 1) {
        t = *(const u16x8*)(ao + ((size_t)bs << 8) + cc);
      } else {
        int b = bs >> 12, s = bs & 4095, head = cc >> 6;
        int li = (b * 4 + head) * Ss + s;
        float accv[8] = {0.f, 0.f, 0.f, 0.f, 0.f, 0.f, 0.f, 0.f};
        float lsum = 0.f;
        for (int spl = 0; spl < nsplit; spl++) {
          float l = lpart[(size_t)spl * (16 * Ss) + li];
          u16x8 a = *(const u16x8*)(AOP + (size_t)spl * ELEMS + ((size_t)bs << 8) + cc);
          lsum += l;
#pragma unroll
          for (int i = 0; i < 8; i++) accv[i] += l * bf2f(a[i]);
        }
        float inv = 1.0f / lsum;
#pragma unroll
        for (int i = 0; i < 8; i++) t[i] = f2bf(accv[i] * inv);
      }
      *(u16x8*)&Bs[row][seg * 8] = t;
    }
    __syncthreads();
    bf16x8 a[4], b[4];
#pragma unroll
    for (int mt = 0; mt < 4; mt++) a[mt] = ldfrag(&As[wm * 64 + mt * 16 + lr][quad * 8]);
#pragma unroll
    for (int nt = 0; nt < 4; nt++) b[nt] = ldfrag(&Bs[wn * 64 + nt * 16 + lr][quad * 8]);
#pragma unroll
    for (int mt = 0; mt < 4; mt++)
#pragma unroll
      for (int nt = 0; nt < 4; nt++)
        acc[mt][nt] = __builtin_amdgcn_mfma_f32_16x16x32_bf16(a[mt], b[nt], acc[mt][nt], 0, 0, 0);
  }
#pragma unroll
  for (int mt = 0; mt < 4; mt++)
#pragma unroll
    for (int rg = 0; rg < 4; rg++) {
      int c = m0 + wm * 64 + mt * 16 + quad * 4 + rg;
      float bc = bo[c];
#pragma unroll
      for (int nt = 0; nt < 4; nt++) {
        int col = n0 + wn * 64 + nt * 16 + lr;
        int b_ = col >> 12, s = col & 4095;
        y[((size_t)(b_ * Cc + c) << 12) + s] = acc[mt][nt][rg] + bc;
      }
    }
}

extern "C" void kernel_launch(void* const* d_in, const int* in_sizes, int n_in,
                              void* d_out, int out_size, void* d_ws, size_t ws_size,
                              hipStream_t stream) {
  const float* x = (const float*)d_in[0];
  const float* w_qkv = (const float*)d_in[1];
  const float* b_qkv = (const float*)d_in[2];
  const float* w_o = (const float*)d_in[3];
  const float* b_o = (const float*)d_in[4];
  float* y = (float*)d_out;
  u16* ws = (u16*)d_ws;
  u16* xt = ws;                        // [0, E) — reused as ao (nsplit==1 fallback)
  u16* q = ws + (size_t)ELEMS;
  u16* k = ws + (size_t)2 * ELEMS;
  u16* vt = ws + (size_t)3 * ELEMS;
  u16* ao = xt;
  u16* wqb = ws + (size_t)4 * ELEMS;   // 196608
  u16* wob = wqb + 196608;             // 65536
  const size_t Wu16 = (size_t)4 * ELEMS + 262144;
  // need(n) bytes = bf16 ws incl. n partial slabs, + n*16*Ss f32 for lpart
  auto need = [&](int n) { return (Wu16 + (size_t)n * ELEMS) * 2 + (size_t)n * 16 * Ss * 4; };
  const int nsplit = (ws_size >= need(2)) ? 2 : 1;
  u16* aop = ws + Wu16;                // nsplit*ELEMS u16 normalized partials
  u16* v = aop;                        // plain V aliases aop (dead before k_attn writes)
  float* lpart = (float*)(aop + (size_t)nsplit * ELEMS);

  k_transpose<<<dim3(64, 4, 4), 256, 0, stream>>>(x, xt, w_qkv, w_o, wqb, wob);
  k_qkv<<<dim3(128, 6), 256, 0, stream>>>(xt, wqb, b_qkv, q, k, v);
  k_vt<<<dim3(64, 16), 256, 0, stream>>>(v, vt);
  k_attn<<<dim3(16, 16, nsplit), 512, 0, stream>>>(q, k, vt, ao, aop, lpart, nsplit);
  k_oproj<<<dim3(128, 2), 256, 0, stream>>>(wob, ao, aop, lpart, b_o, y, nsplit);
}

// Round 7
// 177.098 us; speedup vs baseline: 1.0931x; 1.0108x over previous
//
#include <hip/hip_runtime.h>
#include <stdint.h>

#define DI __device__ __forceinline__

typedef __attribute__((ext_vector_type(8))) __bf16 bf16x8;
typedef __attribute__((ext_vector_type(8))) unsigned short u16x8;
typedef __attribute__((ext_vector_type(4))) float f32x4;
typedef __attribute__((ext_vector_type(4))) uint32_t u32x4;
typedef unsigned short u16;

constexpr int Bb = 4, Cc = 256, Ss = 4096, HD = 64;
constexpr int ELEMS = Bb * Cc * Ss;  // 4194304

DI float bf2f(u16 h) { union { unsigned u; float f; } x; x.u = ((unsigned)h) << 16; return x.f; }
DI u16 f2bf(float f) {
  union { float f; unsigned u; } x; x.f = f;
  return (u16)((x.u + 0x7FFFu + ((x.u >> 16) & 1u)) >> 16);
}
DI uint32_t pack2bf_trunc(float a, float b) {  // low16=bf(a), high16=bf(b), truncating
  union { float f; uint32_t u; } xa, xb;
  xa.f = a; xb.f = b;
  return __builtin_amdgcn_perm(xb.u, xa.u, 0x07060302u);
}
DI bf16x8 ldfrag(const u16* p) { return __builtin_bit_cast(bf16x8, *(const u16x8*)p); }

// async global->LDS DMA, 16B per lane. LDS dest = wave-uniform base + lane*16 (linear);
// source address is per-lane (carries the swizzle).
DI void g2l16(const u16* g, u16* l) {
  __builtin_amdgcn_global_load_lds((const __attribute__((address_space(1))) uint32_t*)(const void*)g,
                                   (__attribute__((address_space(3))) uint32_t*)(void*)l, 16, 0, 0);
}

// ---------------- kernel 0: x (B,C,S) fp32 -> xt (B,S,C) bf16; + weight conversion fused ----------------
__global__ __launch_bounds__(256) void k_transpose(const float* __restrict__ x, u16* __restrict__ xt,
                                                   const float* __restrict__ wq, const float* __restrict__ wo,
                                                   u16* __restrict__ wqb, u16* __restrict__ wob) {
  __shared__ u16 T[64][72];
  const int st = blockIdx.x, ct = blockIdx.y, b = blockIdx.z;
  const int tid = threadIdx.x;
  // fused weight conversion: 1024 blocks x 256 threads == 262144 == 196608 + 65536
  {
    int flat = blockIdx.x + 64 * blockIdx.y + 256 * blockIdx.z;
    int widx = flat * 256 + tid;
    if (widx < 196608) wqb[widx] = f2bf(wq[widx]);
    else wob[widx - 196608] = f2bf(wo[widx - 196608]);
  }
#pragma unroll
  for (int e = 0; e < 2; e++) {
    int ss = tid + e * 256;
    int r = ss >> 3, seg = ss & 7;
    size_t base = ((size_t)(b * Cc + ct * 64 + r) << 12) + st * 64 + seg * 8;
    u16x8 t;
#pragma unroll
    for (int j = 0; j < 8; j++) t[j] = f2bf(x[base + j]);
    *(u16x8*)&T[r][(seg ^ ((r >> 3) & 7)) * 8] = t;
  }
  __syncthreads();
#pragma unroll
  for (int e = 0; e < 2; e++) {
    int ss = tid + e * 256;
    int sr = ss >> 3, cseg = ss & 7;
    u16x8 o;
#pragma unroll
    for (int j = 0; j < 8; j++) {
      int row = cseg * 8 + j;
      o[j] = T[row][(((sr >> 3) ^ cseg) * 8) + (sr & 7)];
    }
    *(u16x8*)(xt + ((size_t)(b * Ss + st * 64 + sr) << 8) + ct * 64 + cseg * 8) = o;
  }
}

// ---- shared GEMM staging: rows [r0,r0+128) x cols [k0,k0+32), pitch-40 LDS ----
DI void stage_tile(const u16* __restrict__ src, int pitch, int r0, int k0, u16 (*dst)[40], int tid) {
#pragma unroll
  for (int e = 0; e < 2; e++) {
    int c = tid + e * 256;
    int row = c >> 2, seg = c & 3;
    u16x8 t = *(const u16x8*)(src + (size_t)(r0 + row) * pitch + k0 + seg * 8);
    *(u16x8*)&dst[row][seg * 8] = t;
  }
}

// ---------------- kernel 1: qkv GEMM + fused V-transpose ----------------
// q:[bh][s][64]*(0.125*log2e)  k:[bh][s][64]  v -> vt [bh][d][chunk*64+slot] directly.
// part is uniform per block (blockIdx.y>>1). V-blocks (by>=4) stage the 128x128 acc tile to
// LDS (union'd with As/Bs), re-read transposed + slot-permuted (k_vt's sw mapping), and write
// vt with 256B-contiguous u16x8 segments — deletes the separate k_vt kernel and the v
// intermediate (33 MB of HBM round-trip).
__global__ __launch_bounds__(256) void k_qkv(const u16* __restrict__ xt, const u16* __restrict__ w,
                                             const float* __restrict__ bias,
                                             u16* __restrict__ q, u16* __restrict__ kk_, u16* __restrict__ vt) {
  __shared__ union {
    u16 ab[2][128][40];   // As, Bs during K-loop
    u16 vtile[128][132];  // V epilogue transpose buffer (33 KB)
  } sm;
  const int tid = threadIdx.x;
  const int wv = tid >> 6, lane = tid & 63;
  const int wm = wv >> 1, wn = wv & 1;
  const int lr = lane & 15, quad = lane >> 4;
  const int r0 = blockIdx.x * 128;
  const int j0 = blockIdx.y * 128;
  f32x4 acc[4][4] = {};
  for (int k0 = 0; k0 < 256; k0 += 32) {
    __syncthreads();
    stage_tile(xt, 256, r0, k0, sm.ab[0], tid);
    stage_tile(w, 256, j0, k0, sm.ab[1], tid);
    __syncthreads();
    bf16x8 a[4], b[4];
#pragma unroll
    for (int mt = 0; mt < 4; mt++) a[mt] = ldfrag(&sm.ab[0][wm * 64 + mt * 16 + lr][quad * 8]);
#pragma unroll
    for (int nt = 0; nt < 4; nt++) b[nt] = ldfrag(&sm.ab[1][wn * 64 + nt * 16 + lr][quad * 8]);
#pragma unroll
    for (int mt = 0; mt < 4; mt++)
#pragma unroll
      for (int nt = 0; nt < 4; nt++)
        acc[mt][nt] = __builtin_amdgcn_mfma_f32_16x16x32_bf16(a[mt], b[nt], acc[mt][nt], 0, 0, 0);
  }
  if (blockIdx.y < 4) {
    // q/k path: part uniform per block
    const int part = blockIdx.y >> 1;  // 0=q, 1=k
    u16* outp = part ? kk_ : q;
    const float sc = part ? 1.0f : 0.18033688f;  // 0.125*log2(e), exp2-domain scores
#pragma unroll
    for (int nt = 0; nt < 4; nt++) {
      int j = j0 + wn * 64 + nt * 16 + lr;
      float bj = bias[j];
      int cc = j & 255, head = cc >> 6, d = cc & 63;
#pragma unroll
      for (int mt = 0; mt < 4; mt++)
#pragma unroll
        for (int rg = 0; rg < 4; rg++) {
          int row = r0 + wm * 64 + mt * 16 + quad * 4 + rg;
          int b_ = row >> 12, s = row & 4095;
          outp[((size_t)((b_ * 4 + head) * Ss + s) << 6) + d] = f2bf((acc[mt][nt][rg] + bj) * sc);
        }
    }
  } else {
    // v path: acc tile -> LDS -> transposed+permuted vt write
    const int hb = (blockIdx.y - 4) * 2;  // head base (0 or 2)
    float bj[4];
#pragma unroll
    for (int nt = 0; nt < 4; nt++) bj[nt] = bias[j0 + wn * 64 + nt * 16 + lr];
    __syncthreads();  // all MFMA ldfrags of As/Bs done before overwriting the union
#pragma unroll
    for (int nt = 0; nt < 4; nt++) {
      int lc = wn * 64 + nt * 16 + lr;
#pragma unroll
      for (int mt = 0; mt < 4; mt++)
#pragma unroll
        for (int rg = 0; rg < 4; rg++)
          sm.vtile[wm * 64 + mt * 16 + quad * 4 + rg][lc] = f2bf(acc[mt][nt][rg] + bj[nt]);
    }
    __syncthreads();
    const int b2 = r0 >> 12, sbase = r0 & 4095;
#pragma unroll
    for (int it = 0; it < 8; it++) {
      int seg = tid + it * 256;        // 2048 u16x8 segments
      int sq = seg & 15, hd = seg >> 4;  // consecutive tids -> consecutive slots (coalesced)
      int c = sq >> 3, s8 = sq & 7;
      u16x8 o;
#pragma unroll
      for (int j = 0; j < 8; j++) {
        int slot = s8 * 8 + j;
        int sw = (((slot >> 5) & 1) << 5) | (((slot >> 2) & 1) << 4) |
                 (((slot >> 3) & 3) << 2) | (slot & 3);  // k_vt's w6 bijection
        o[j] = sm.vtile[c * 64 + sw][hd];
      }
      int head = hb + (hd >> 6), d = hd & 63;
      *(u16x8*)(vt + ((size_t)((b2 * 4 + head) * 64 + d) << 12) + sbase + c * 64 + s8 * 8) = o;
    }
  }
}

// ---------------- kernel 2: flash attention, S^T form, exp2 no-max softmax ----------------
// 8-wave (512-thread) blocks of 32-q waves, 256 q-rows/block; 4 waves/SIMD (r6 structure,
// best measured). l on the ones-MFMA. Staging: one g2l16 per thread per tile, pre-swizzled
// source. grid (16,16,2) = 512 blocks; LDS 32KB; VGPR 52.
__global__ __launch_bounds__(512, 4) void k_attn(const u16* __restrict__ Q, const u16* __restrict__ K,
                                                 const u16* __restrict__ VT, u16* __restrict__ AO,
                                                 u16* __restrict__ AOP, float* __restrict__ lpart,
                                                 int nsplit) {
  __shared__ u16 Kl[2][64][64];
  __shared__ u16 Vl[2][64][64];
  const int tid = threadIdx.x;
  const int wv = tid >> 6, lane = tid & 63;
  const int lr = lane & 15, quad = lane >> 4;
  const int bh = blockIdx.y;
  const int b_ = bh >> 2, head = bh & 3;
  const int qbase = blockIdx.x * 256 + wv * 32;
  const int sp = blockIdx.z;
  const int nchunk = 64 / nsplit, kcg0 = sp * nchunk;
  const u16* Qh = Q + (size_t)bh * Ss * HD;
  const u16* Kh = K + (size_t)bh * Ss * HD;
  const u16* Vh = VT + (size_t)bh * HD * Ss;  // [d][perm(s)]

  bf16x8 qb[2][2];
#pragma unroll
  for (int nt = 0; nt < 2; nt++)
#pragma unroll
    for (int ks = 0; ks < 2; ks++)
      qb[nt][ks] = ldfrag(Qh + (size_t)(qbase + nt * 16 + lr) * HD + ks * 32 + quad * 8);

  u16x8 ov;
#pragma unroll
  for (int j = 0; j < 8; j++) ov[j] = 0x3F80;
  const bf16x8 ones = __builtin_bit_cast(bf16x8, ov);

  f32x4 O[2][4] = {};
  f32x4 lacc[2] = {};

  // DMA staging: 8 waves cover 64 rows (wave wv: rows wv*8..wv*8+7). Lane l writes LDS
  // granule (row = wv*8 + l>>3, slot = l&7); source granule = (l&7) ^ (row&7) = (l&7)^(l>>3).
  const int srow = wv * 8 + (lane >> 3);
  const int sseg = ((lane & 7) ^ (lane >> 3)) * 8;
  const u16* pK = Kh + ((size_t)(kcg0 * 64 + srow) << 6) + sseg;
  const u16* pV = Vh + ((size_t)srow << 12) + kcg0 * 64 + sseg;
  auto stage = [&](int buf) {
    g2l16(pK, &Kl[buf][wv * 8][0]);
    g2l16(pV, &Vl[buf][wv * 8][0]);
    pK += 4096; pV += 64;  // next chunk
  };

  stage(0);
  __syncthreads();

  for (int kc = 0; kc < nchunk; kc++) {
    const int cur = kc & 1;
    if (kc + 1 < nchunk) stage(cur ^ 1);  // async into other buffer; drains at loop-end barrier

    u32x4 pa[2][2];  // [kv-half][q-group]: packed bf16 P fragments (PV A-operands)
#pragma unroll
    for (int t = 0; t < 4; t++) {  // 16-row kv tiles
      const int krow = t * 16 + lr;
      bf16x8 ka0 = ldfrag(&Kl[cur][krow][(quad ^ (lr & 7)) * 8]);
      bf16x8 ka1 = ldfrag(&Kl[cur][krow][((4 + quad) ^ (lr & 7)) * 8]);
      f32x4 St[2] = {};
      __builtin_amdgcn_s_setprio(1);
#pragma unroll
      for (int nt = 0; nt < 2; nt++)
        St[nt] = __builtin_amdgcn_mfma_f32_16x16x32_bf16(ka0, qb[nt][0], St[nt], 0, 0, 0);
#pragma unroll
      for (int nt = 0; nt < 2; nt++)
        St[nt] = __builtin_amdgcn_mfma_f32_16x16x32_bf16(ka1, qb[nt][1], St[nt], 0, 0, 0);
      __builtin_amdgcn_s_setprio(0);
      const int h = t >> 1, k2 = (t & 1) * 2;
#pragma unroll
      for (int nt = 0; nt < 2; nt++) {
        float p0 = __builtin_amdgcn_exp2f(St[nt][0]);
        float p1 = __builtin_amdgcn_exp2f(St[nt][1]);
        float p2 = __builtin_amdgcn_exp2f(St[nt][2]);
        float p3 = __builtin_amdgcn_exp2f(St[nt][3]);
        pa[h][nt][k2] = pack2bf_trunc(p0, p1);
        pa[h][nt][k2 + 1] = pack2bf_trunc(p2, p3);
      }
    }
#pragma unroll
    for (int h = 0; h < 2; h++) {
#pragma unroll
      for (int dt = 0; dt < 4; dt++) {
        bf16x8 vb = ldfrag(&Vl[cur][dt * 16 + lr][((h * 4 + quad) ^ (lr & 7)) * 8]);
        __builtin_amdgcn_s_setprio(1);
#pragma unroll
        for (int mt = 0; mt < 2; mt++)
          O[mt][dt] = __builtin_amdgcn_mfma_f32_16x16x32_bf16(
              __builtin_bit_cast(bf16x8, pa[h][mt]), vb, O[mt][dt], 0, 0, 0);
        __builtin_amdgcn_s_setprio(0);
      }
#pragma unroll
      for (int mt = 0; mt < 2; mt++)
        lacc[mt] = __builtin_amdgcn_mfma_f32_16x16x32_bf16(
            __builtin_bit_cast(bf16x8, pa[h][mt]), ones, lacc[mt], 0, 0, 0);
    }
    __syncthreads();
  }

  // epilogue: normalize by this split's l, write bf16 (AO if nsplit==1, else partial slot sp)
  u16* dst = (nsplit == 1) ? AO : (AOP + (size_t)sp * ELEMS);
  if (nsplit > 1 && lr == 0) {
    float* lp = lpart + (size_t)sp * (16 * Ss) + bh * Ss;
#pragma unroll
    for (int mt = 0; mt < 2; mt++)
#pragma unroll
      for (int rg = 0; rg < 4; rg++) lp[qbase + mt * 16 + quad * 4 + rg] = lacc[mt][rg];
  }
#pragma unroll
  for (int mt = 0; mt < 2; mt++)
#pragma unroll
    for (int rg = 0; rg < 4; rg++) {
      float inv = 1.0f / lacc[mt][rg];
      int s = qbase + mt * 16 + quad * 4 + rg;
#pragma unroll
      for (int dt = 0; dt < 4; dt++)
        dst[((size_t)(b_ * Ss + s) << 8) + head * 64 + dt * 16 + lr] = f2bf(O[mt][dt][rg] * inv);
    }
}

// ---------------- kernel 3 (fused combine + oproj): y^T = w_o * combine(aop)^T + b_o ----------------
__global__ __launch_bounds__(256) void k_oproj(const u16* __restrict__ wo, const u16* __restrict__ ao,
                                               const u16* __restrict__ AOP, const float* __restrict__ lpart,
                                               const float* __restrict__ bo, float* __restrict__ y, int nsplit) {
  __shared__ u16 As[128][40], Bs[128][40];
  const int tid = threadIdx.x;
  const int wv = tid >> 6, lane = tid & 63;
  const int wm = wv >> 1, wn = wv & 1;
  const int lr = lane & 15, quad = lane >> 4;
  const int n0 = blockIdx.x * 128;
  const int m0 = blockIdx.y * 128;
  f32x4 acc[4][4] = {};
  for (int k0 = 0; k0 < 256; k0 += 32) {
    __syncthreads();
    stage_tile(wo, 256, m0, k0, As, tid);
#pragma unroll
    for (int e = 0; e < 2; e++) {  // B: 128 n-rows x 32 c-cols, l-weighted combine
      int c = tid + e * 256;
      int row = c >> 2, seg = c & 3;
      int bs = n0 + row, cc = k0 + seg * 8;
      u16x8 t;
      if (nsplit == 1) {
        t = *(const u16x8*)(ao + ((size_t)bs << 8) + cc);
      } else {
        int b = bs >> 12, s = bs & 4095, head = cc >> 6;
        int li = (b * 4 + head) * Ss + s;
        float accv[8] = {0.f, 0.f, 0.f, 0.f, 0.f, 0.f, 0.f, 0.f};
        float lsum = 0.f;
        for (int spl = 0; spl < nsplit; spl++) {
          float l = lpart[(size_t)spl * (16 * Ss) + li];
          u16x8 a = *(const u16x8*)(AOP + (size_t)spl * ELEMS + ((size_t)bs << 8) + cc);
          lsum += l;
#pragma unroll
          for (int i = 0; i < 8; i++) accv[i] += l * bf2f(a[i]);
        }
        float inv = 1.0f / lsum;
#pragma unroll
        for (int i = 0; i < 8; i++) t[i] = f2bf(accv[i] * inv);
      }
      *(u16x8*)&Bs[row][seg * 8] = t;
    }
    __syncthreads();
    bf16x8 a[4], b[4];
#pragma unroll
    for (int mt = 0; mt < 4; mt++) a[mt] = ldfrag(&As[wm * 64 + mt * 16 + lr][quad * 8]);
#pragma unroll
    for (int nt = 0; nt < 4; nt++) b[nt] = ldfrag(&Bs[wn * 64 + nt * 16 + lr][quad * 8]);
#pragma unroll
    for (int mt = 0; mt < 4; mt++)
#pragma unroll
      for (int nt = 0; nt < 4; nt++)
        acc[mt][nt] = __builtin_amdgcn_mfma_f32_16x16x32_bf16(a[mt], b[nt], acc[mt][nt], 0, 0, 0);
  }
#pragma unroll
  for (int mt = 0; mt < 4; mt++)
#pragma unroll
    for (int rg = 0; rg < 4; rg++) {
      int c = m0 + wm * 64 + mt * 16 + quad * 4 + rg;
      float bc = bo[c];
#pragma unroll
      for (int nt = 0; nt < 4; nt++) {
        int col = n0 + wn * 64 + nt * 16 + lr;
        int b_ = col >> 12, s = col & 4095;
        y[((size_t)(b_ * Cc + c) << 12) + s] = acc[mt][nt][rg] + bc;
      }
    }
}

extern "C" void kernel_launch(void* const* d_in, const int* in_sizes, int n_in,
                              void* d_out, int out_size, void* d_ws, size_t ws_size,
                              hipStream_t stream) {
  const float* x = (const float*)d_in[0];
  const float* w_qkv = (const float*)d_in[1];
  const float* b_qkv = (const float*)d_in[2];
  const float* w_o = (const float*)d_in[3];
  const float* b_o = (const float*)d_in[4];
  float* y = (float*)d_out;
  u16* ws = (u16*)d_ws;
  u16* xt = ws;                        // [0, E) — reused as ao (nsplit==1 fallback)
  u16* q = ws + (size_t)ELEMS;
  u16* k = ws + (size_t)2 * ELEMS;
  u16* vt = ws + (size_t)3 * ELEMS;
  u16* ao = xt;
  u16* wqb = ws + (size_t)4 * ELEMS;   // 196608
  u16* wob = wqb + 196608;             // 65536
  const size_t Wu16 = (size_t)4 * ELEMS + 262144;
  // need(n) bytes = bf16 ws incl. n partial slabs, + n*16*Ss f32 for lpart
  auto need = [&](int n) { return (Wu16 + (size_t)n * ELEMS) * 2 + (size_t)n * 16 * Ss * 4; };
  const int nsplit = (ws_size >= need(2)) ? 2 : 1;
  u16* aop = ws + Wu16;                // nsplit*ELEMS u16 normalized partials
  float* lpart = (float*)(aop + (size_t)nsplit * ELEMS);

  k_transpose<<<dim3(64, 4, 4), 256, 0, stream>>>(x, xt, w_qkv, w_o, wqb, wob);
  k_qkv<<<dim3(128, 6), 256, 0, stream>>>(xt, wqb, b_qkv, q, k, vt);
  k_attn<<<dim3(16, 16, nsplit), 512, 0, stream>>>(q, k, vt, ao, aop, lpart, nsplit);
  k_oproj<<<dim3(128, 2), 256, 0, stream>>>(wob, ao, aop, lpart, b_o, y, nsplit);
}